// Round 17
// baseline (303.542 us; speedup 1.0000x reference)
//
#include <hip/hip_runtime.h>

// SPADE ResNet block — bf16 MFMA implicit-GEMM, 32x32x16 MFMA.
// R17 = R14 (best: 284.8us) + K-split for the two 1-block/CU convs (actv0,
// spade1): same CBLK=64 block shape, kc range halved per block, grid z = K
// half -> 512 blocks = 2 blk/CU (R14/R16 law: 2 blk/CU ~ 2x per-CU tput).
// Halves write raw accs as bf16 partials (deterministic, no atomics); cheap
// combine kernels apply bias+relu / SPADE+lrelu. Buffer reuse: actv0 partials
// in {hT, Pext}; spade1 partials in {xt, Pext}.

#define S3 32768
constexpr float EPS = 1e-5f;

typedef __attribute__((ext_vector_type(8))) short s16x8;
typedef __attribute__((ext_vector_type(4))) float f32x4;
typedef __attribute__((ext_vector_type(16))) float f32x16;
typedef __attribute__((ext_vector_type(4))) unsigned short u16x4;
typedef __attribute__((ext_vector_type(8))) unsigned short u16x8;

#define GLL(g, l)                                                        \
  __builtin_amdgcn_global_load_lds(                                      \
      (const __attribute__((address_space(1))) void*)(g),                \
      (__attribute__((address_space(3))) void*)(l), 16, 0, 0)

__device__ __forceinline__ float bf2f(unsigned short u) {
  union { unsigned int i; float f; } v; v.i = ((unsigned int)u) << 16; return v.f;
}
__device__ __forceinline__ unsigned short f2bf(float f) {
  union { float f; unsigned int i; } v; v.f = f;
  unsigned int r = (v.i + 0x7FFFu + ((v.i >> 16) & 1u)) >> 16;
  return (unsigned short)r;
}

// ---------------------------------------------------------------- stats ----
__global__ __launch_bounds__(256) void stats_kernel(const float* __restrict__ x,
                                                    float* __restrict__ mu,
                                                    float* __restrict__ rstd) {
  const int bc = blockIdx.x;
  const float* p = x + (size_t)bc * S3;
  float s = 0.f, s2 = 0.f;
  for (int i = threadIdx.x; i < S3 / 4; i += 256) {
    float4 v = reinterpret_cast<const float4*>(p)[i];
    s  += v.x + v.y + v.z + v.w;
    s2 += v.x * v.x + v.y * v.y + v.z * v.z + v.w * v.w;
  }
  for (int off = 32; off; off >>= 1) {
    s  += __shfl_down(s, off, 64);
    s2 += __shfl_down(s2, off, 64);
  }
  __shared__ float ls[4], ls2[4];
  const int wid = threadIdx.x >> 6;
  if ((threadIdx.x & 63) == 0) { ls[wid] = s; ls2[wid] = s2; }
  __syncthreads();
  if (threadIdx.x == 0) {
    float S = 0.f, S2 = 0.f;
    for (int i = 0; i < 4; ++i) { S += ls[i]; S2 += ls2[i]; }
    const float m = S / (float)S3;
    const float var = S2 / (float)S3 - m * m;
    mu[bc] = m;
    rstd[bc] = rsqrtf(var + EPS);
  }
}

// Stats over bf16 T-layout tensor [B][S3][32] (dx0), phase 1.
__global__ __launch_bounds__(256) void stats_t32_p1(const short* __restrict__ t,
                                                    float* __restrict__ part) {
  const int b = blockIdx.y;
  const int chunk = blockIdx.x;
  const int tid = threadIdx.x;
  const int pq = tid & 3;
  float s[8], s2[8];
#pragma unroll
  for (int j = 0; j < 8; ++j) { s[j] = 0.f; s2[j] = 0.f; }
  const int vbase = chunk * 512;
#pragma unroll
  for (int v = tid >> 2; v < 512; v += 64) {
    u16x8 u = *reinterpret_cast<const u16x8*>(
        &t[((size_t)b * S3 + vbase + v) * 32 + pq * 8]);
#pragma unroll
    for (int j = 0; j < 8; ++j) { float f = bf2f(u[j]); s[j] += f; s2[j] += f * f; }
  }
#pragma unroll
  for (int off = 4; off < 64; off <<= 1) {
#pragma unroll
    for (int j = 0; j < 8; ++j) {
      s[j]  += __shfl_xor(s[j], off, 64);
      s2[j] += __shfl_xor(s2[j], off, 64);
    }
  }
  __shared__ float red[4][4][16];
  const int wv = tid >> 6, lane = tid & 63;
  if (lane < 4) {
#pragma unroll
    for (int j = 0; j < 8; ++j) { red[wv][lane][j] = s[j]; red[wv][lane][8 + j] = s2[j]; }
  }
  __syncthreads();
  if (tid < 32) {
    const int p = tid >> 3, j = tid & 7;
    float S = 0.f, S2 = 0.f;
#pragma unroll
    for (int w = 0; w < 4; ++w) { S += red[w][p][j]; S2 += red[w][p][8 + j]; }
    const int c = p * 8 + j;
    part[((size_t)(b * 64 + chunk)) * 64 + c] = S;
    part[((size_t)(b * 64 + chunk)) * 64 + 32 + c] = S2;
  }
}

__global__ __launch_bounds__(128) void stats_t32_p2(const float* __restrict__ part,
                                                    float* __restrict__ mu,
                                                    float* __restrict__ rstd) {
  const int tid = threadIdx.x;
  const int b = tid >> 5, c = tid & 31;
  float S = 0.f, S2 = 0.f;
#pragma unroll 4
  for (int k = 0; k < 64; ++k) {
    S  += part[((size_t)(b * 64 + k)) * 64 + c];
    S2 += part[((size_t)(b * 64 + k)) * 64 + 32 + c];
  }
  const float m = S / (float)S3;
  const float var = S2 / (float)S3 - m * m;
  mu[b * 32 + c] = m;
  rstd[b * 32 + c] = rsqrtf(var + EPS);
}

// ------------------------------------------------------------ transpose ----
__global__ __launch_bounds__(256) void transpose_x(const float* __restrict__ x,
                                                   short* __restrict__ xt) {
  const int b = blockIdx.y;
  const int v0 = blockIdx.x * 64;
  __shared__ unsigned short t[64][72];
  const int vox = threadIdx.x & 63;
  const int cg = threadIdx.x >> 6;
#pragma unroll
  for (int k = 0; k < 16; ++k) {
    const int ci = cg * 16 + k;
    t[vox][ci] = f2bf(x[((size_t)(b * 64 + ci)) * S3 + v0 + vox]);
  }
  __syncthreads();
  const int vv = threadIdx.x >> 2, part = threadIdx.x & 3;
  uint4 u0 = *reinterpret_cast<const uint4*>(&t[vv][part * 16]);
  uint4 u1 = *reinterpret_cast<const uint4*>(&t[vv][part * 16 + 8]);
  short* dst = &xt[((size_t)(b * S3 + v0 + vv)) * 64 + part * 16];
  *reinterpret_cast<uint4*>(dst) = u0;
  *reinterpret_cast<uint4*>(dst + 8) = u1;
}

// --------------------------------------------------------------- repack ----
// fp32 [cls][CO_src][CI][27] -> bf16 [b][27][KCH=CI/16][CO2][16ci].
__global__ __launch_bounds__(256) void repack_w(
    const float* __restrict__ wA, const float* __restrict__ wB,
    short* __restrict__ dst, const int* __restrict__ y,
    int CBLK, int CO2, int CI, long clsA, long clsB, int paired, int total) {
  const int b = blockIdx.y;
  const int idx = blockIdx.x * 256 + threadIdx.x;
  if (idx >= total) return;
  const int cls = y[b];
  const int KCH = CI / 16;
  const int ci = idx & 15;
  const int co = (idx >> 4) % CO2;
  const int rest = idx / (16 * CO2);
  const int k16 = rest % KCH;
  const int tap = rest / KCH;
  const int srcch = k16 * 16 + ci;
  float v;
  if (paired) {
    const int H = CBLK >> 1;
    const int blk = co / CBLK, w = co % CBLK;
    if (w < H)
      v = wA[(size_t)clsA * cls + ((size_t)(blk * H + w) * CI + srcch) * 27 + tap];
    else
      v = wB[(size_t)clsB * cls + ((size_t)(blk * H + w - H) * CI + srcch) * 27 + tap];
  } else {
    v = wA[(size_t)clsA * cls + ((size_t)co * CI + srcch) * 27 + tap];
  }
  dst[(((size_t)(b * 27 + tap) * KCH + k16) * CO2 + co) * 16 + ci] = (short)f2bf(v);
}

// -------------------------------------------------------------- combine ----
// actvT = relu(P0 + P1 + bias)   over [B][S3][64]
__global__ __launch_bounds__(256) void combine_actv(
    const short* __restrict__ P0, const short* __restrict__ P1,
    const float* __restrict__ bias, const int* __restrict__ y,
    short* __restrict__ dst) {
  const int b = blockIdx.y;
  const int cls = y[b];
  const size_t e = ((size_t)blockIdx.x * 256 + threadIdx.x) * 8;
  const int c = (int)(e & 63);
  const size_t g = (size_t)b * S3 * 64 + e;
  u16x8 a = *reinterpret_cast<const u16x8*>(&P0[g]);
  u16x8 bb = *reinterpret_cast<const u16x8*>(&P1[g]);
  u16x8 o;
#pragma unroll
  for (int j = 0; j < 8; ++j) {
    float v = bf2f(a[j]) + bf2f(bb[j]) + bias[cls * 64 + c + j];
    o[j] = f2bf(fmaxf(v, 0.f));
  }
  *reinterpret_cast<u16x8*>(&dst[g]) = o;
}

// hT = lrelu( (d0T - mu)*rstd * (1 + gamma) + beta )  over [B][S3][32]
// gamma = P0[.][c]+P1[.][c]+bg[c], beta = P0[.][c+32]+P1[.][c+32]+bb[c]
__global__ __launch_bounds__(256) void combine_spade(
    const short* __restrict__ P0, const short* __restrict__ P1,
    const short* __restrict__ xn, const float* __restrict__ mu,
    const float* __restrict__ rstd, const float* __restrict__ bgs,
    const float* __restrict__ bbs, const int* __restrict__ y,
    short* __restrict__ dst) {
  const int b = blockIdx.y;
  const int cls = y[b];
  const int idx = blockIdx.x * 256 + threadIdx.x;   // voxel*4 + part
  const int v = idx >> 2, part = idx & 2, c = (idx & 3) * 8;
  (void)part;
  const size_t b64 = ((size_t)b * S3 + v) * 64;
  const size_t b32 = ((size_t)b * S3 + v) * 32;
  u16x8 g0 = *reinterpret_cast<const u16x8*>(&P0[b64 + c]);
  u16x8 g1 = *reinterpret_cast<const u16x8*>(&P1[b64 + c]);
  u16x8 t0 = *reinterpret_cast<const u16x8*>(&P0[b64 + 32 + c]);
  u16x8 t1 = *reinterpret_cast<const u16x8*>(&P1[b64 + 32 + c]);
  u16x8 x8 = *reinterpret_cast<const u16x8*>(&xn[b32 + c]);
  u16x8 o;
#pragma unroll
  for (int j = 0; j < 8; ++j) {
    const int ch = c + j;
    const float gamma = bf2f(g0[j]) + bf2f(g1[j]) + bgs[cls * 32 + ch];
    const float beta  = bf2f(t0[j]) + bf2f(t1[j]) + bbs[cls * 32 + ch];
    const float nrm = (bf2f(x8[j]) - mu[b * 32 + ch]) * rstd[b * 32 + ch];
    float h = nrm * (1.f + gamma) + beta;
    h = h > 0.f ? h : 0.2f * h;
    o[j] = f2bf(h);
  }
  *reinterpret_cast<u16x8*>(&dst[b32 + c]) = o;
}

// ------------------------------------------------------------ conv MFMA ----
// 8x8x8 tile, 4 waves, wave = CBLK co x 128 vox (VG=4). Per phase (kc,kd):
// sync; stage W (9 taps, lane-order) + X (kd==0, two-plane); sync; compute.
// KSPL: 1 = z splits CO (co_base = z*CBLK); 2 = z splits K (kc half), CBLK=CO.
// EPI: 0 relu+bias->bf16T  1 bias->bf16T  2 SPADE+lrelu->bf16T (NCOG=2)
//      4 bias+accumulate fp32 planar  5 raw acc -> bf16T partial (z picks buf)
template <int CIN, int CBLK, int COTOT, int EPI, int NNORM, int KSPL = 1>
__global__ __launch_bounds__(256, 2) void conv_mfma(
    const short* __restrict__ xt,      // [B][S3][CIN] bf16
    const short* __restrict__ W,       // [B][27][KCH][COTOT][16] bf16
    const float* __restrict__ bias,
    int bias_stride,
    const int* __restrict__ y,
    const short* __restrict__ xnb,     // EPI2: bf16 T [B][S3][NNORM]
    const float* __restrict__ mu,
    const float* __restrict__ rstd,
    const float* __restrict__ bgs,     // [NCLS][NNORM]
    const float* __restrict__ bbs,
    const short* __restrict__ zp,      // 4KB zero page
    float* __restrict__ outf,          // EPI4
    short* __restrict__ outb,          // EPI 0..2, EPI5 z==0
    short* __restrict__ outb2) {       // EPI5 z==1
  constexpr int KCH = CIN / 16;
  constexpr int NCOG = CBLK / 32;
  constexpr int WG = 9 * NCOG * 64;                       // real W granules
  constexpr int WGP = ((WG + 255) / 256) * 256;           // padded
  constexpr int WISS = WGP / 256;

  __shared__ short ldsX[2048 * 8];     // [plane(khf)*1024 + halo slot][8]
  __shared__ short ldsW[WGP * 8];      // [(t9*NCOG+c)*64 + laneq][8]

  const int tid = threadIdx.x;
  const int lane = tid & 63, wid = tid >> 6;
  const int l31 = lane & 31, khf = lane >> 5;
  const int b = blockIdx.y;
  const int cls = y[b];
  const int co_base = (KSPL == 1) ? blockIdx.z * CBLK : 0;
  const int kc0 = (KSPL == 1) ? 0 : blockIdx.z * (KCH / KSPL);
  // XCD-aware tile swizzle: 64 tiles, 8 XCDs -> each XCD gets 8 contiguous
  const int tile = (blockIdx.x & 7) * 8 + (blockIdx.x >> 3);
  const int d0 = (tile >> 4) * 8, h0 = ((tile >> 2) & 3) * 8, w0 = (tile & 3) * 8;

  // X staging sources: granule i -> plane pl = i>>10, slot = i&1023 (10^3 halo)
  const short* gsrc[8];
#pragma unroll
  for (int k = 0; k < 8; ++k) {
    const int i = tid + k * 256;
    const int pl = i >> 10, slot = i & 1023;
    const short* g = zp;
    if (slot < 1000) {
      const int sd = slot / 100, r0 = slot - sd * 100;
      const int sh = r0 / 10, sw0 = r0 - sh * 10;
      const int gd = d0 + sd - 1, gh = h0 + sh - 1, gw = w0 + sw0 - 1;
      if ((unsigned)gd < 32u && (unsigned)gh < 32u && (unsigned)gw < 32u)
        g = xt + ((size_t)b * S3 + gd * 1024 + gh * 32 + gw) * CIN + pl * 8;
    }
    gsrc[k] = g;
  }

  auto stage_x = [&](int kc) {
#pragma unroll
    for (int k = 0; k < 8; ++k) {
      const int i = tid + k * 256;
      GLL(gsrc[k] + kc * 16, &ldsX[i * 8]);
    }
  };
  auto stage_w = [&](int kc, int kd) {
#pragma unroll
    for (int k = 0; k < WISS; ++k) {
      const int i = tid + k * 256;
      const short* g = zp;
      if (i < WG) {
        const int t9 = i / (NCOG * 64);
        const int r = i - t9 * (NCOG * 64);
        const int c = r >> 6, q = r & 63;
        g = W + (((size_t)(b * 27 + kd * 9 + t9) * KCH + kc) * COTOT +
                 co_base + c * 32 + (q & 31)) * 16 + (q >> 5) * 8;
      }
      GLL(g, &ldsW[i * 8]);
    }
  };

  f32x16 acc[4][NCOG];
#pragma unroll
  for (int v = 0; v < 4; ++v)
#pragma unroll
    for (int c = 0; c < NCOG; ++c)
#pragma unroll
      for (int r = 0; r < 16; ++r) acc[v][c][r] = 0.f;

  const int hw10 = (l31 >> 3) * 10 + (l31 & 7);
  const int xpl = khf * 1024;

#pragma unroll 1
  for (int kci = 0; kci < KCH / KSPL; ++kci) {
    const int kc = kc0 + kci;
#pragma unroll 1
    for (int kd = 0; kd < 3; ++kd) {
      __syncthreads();
      stage_w(kc, kd);
      if (kd == 0) stage_x(kc);
      __syncthreads();

      __builtin_amdgcn_s_setprio(1);
#pragma unroll
      for (int kh = 0; kh < 3; ++kh) {
#pragma unroll
        for (int kw = 0; kw < 3; ++kw) {
          const int t9 = kh * 3 + kw;
          s16x8 af[NCOG];
#pragma unroll
          for (int c = 0; c < NCOG; ++c)
            af[c] = *reinterpret_cast<const s16x8*>(
                &ldsW[((t9 * NCOG + c) * 64 + lane) * 8]);
          s16x8 bf[4];
#pragma unroll
          for (int vg = 0; vg < 4; ++vg) {
            const int slot = (2 * wid + (vg >> 1) + kd) * 100 +
                             ((vg & 1) * 4 + kh) * 10 + kw + hw10;
            bf[vg] = *reinterpret_cast<const s16x8*>(&ldsX[(xpl + slot) * 8]);
          }
#pragma unroll
          for (int c = 0; c < NCOG; ++c)
#pragma unroll
            for (int vg = 0; vg < 4; ++vg)
              acc[vg][c] = __builtin_amdgcn_mfma_f32_32x32x16_bf16(
                  af[c], bf[vg], acc[vg][c], 0, 0, 0);
        }
      }
      __builtin_amdgcn_s_setprio(0);
    }
  }

  // epilogue. C: col = lane&31 -> voxel, row = (reg&3)+8*(reg>>2)+4*khf -> co.
  const int vdb = d0 + 2 * wid;
  const int vhb = h0 + (l31 >> 3);
  const int vwb = w0 + (l31 & 7);

  if constexpr (EPI == 0 || EPI == 1) {
#pragma unroll
    for (int c = 0; c < NCOG; ++c)
#pragma unroll
      for (int q = 0; q < 4; ++q) {
        const int c0 = co_base + c * 32 + q * 8 + khf * 4;
        const f32x4 b4 = *reinterpret_cast<const f32x4*>(&bias[cls * bias_stride + c0]);
#pragma unroll
        for (int vg = 0; vg < 4; ++vg) {
          const int gv = (vdb + (vg >> 1)) * 1024 + (vhb + (vg & 1) * 4) * 32 + vwb;
          u16x4 o;
#pragma unroll
          for (int rr = 0; rr < 4; ++rr) {
            float v = acc[vg][c][q * 4 + rr] + b4[rr];
            if constexpr (EPI == 0) v = fmaxf(v, 0.f);
            o[rr] = f2bf(v);
          }
          *reinterpret_cast<u16x4*>(&outb[((size_t)b * S3 + gv) * COTOT + c0]) = o;
        }
      }
  }

  if constexpr (EPI == 2) {
    const int nb = blockIdx.z * 32;      // gamma = acc[.][0], beta = acc[.][1]
#pragma unroll
    for (int q = 0; q < 4; ++q) {
      const int c0 = nb + q * 8 + khf * 4;
      const f32x4 m4  = *reinterpret_cast<const f32x4*>(&mu[b * NNORM + c0]);
      const f32x4 r4  = *reinterpret_cast<const f32x4*>(&rstd[b * NNORM + c0]);
      const f32x4 g4  = *reinterpret_cast<const f32x4*>(&bgs[cls * NNORM + c0]);
      const f32x4 bb4 = *reinterpret_cast<const f32x4*>(&bbs[cls * NNORM + c0]);
#pragma unroll
      for (int vg = 0; vg < 4; ++vg) {
        const int gv = (vdb + (vg >> 1)) * 1024 + (vhb + (vg & 1) * 4) * 32 + vwb;
        const size_t vgl = (size_t)b * S3 + gv;
        u16x4 u = *reinterpret_cast<const u16x4*>(&xnb[vgl * NNORM + c0]);
        u16x4 o;
#pragma unroll
        for (int rr = 0; rr < 4; ++rr) {
          const float gamma = acc[vg][0][q * 4 + rr] + g4[rr];
          const float beta  = acc[vg][1][q * 4 + rr] + bb4[rr];
          const float nrm = (bf2f(u[rr]) - m4[rr]) * r4[rr];
          float h = nrm * (1.f + gamma) + beta;
          h = h > 0.f ? h : 0.2f * h;
          o[rr] = f2bf(h);
        }
        *reinterpret_cast<u16x4*>(&outb[vgl * NNORM + c0]) = o;
      }
    }
  }

  if constexpr (EPI == 4) {
#pragma unroll
    for (int q = 0; q < 4; ++q) {
      const int c0 = co_base + q * 8 + khf * 4;
      const f32x4 b4 = *reinterpret_cast<const f32x4*>(&bias[c0]);
#pragma unroll
      for (int vg = 0; vg < 4; ++vg) {
        const int gv = (vdb + (vg >> 1)) * 1024 + (vhb + (vg & 1) * 4) * 32 + vwb;
#pragma unroll
        for (int rr = 0; rr < 4; ++rr) {
          float* p = &outf[((size_t)(b * 32 + c0 + rr)) * S3 + gv];
          *p += acc[vg][0][q * 4 + rr] + b4[rr];
        }
      }
    }
  }

  if constexpr (EPI == 5) {
    short* dst = blockIdx.z ? outb2 : outb;
#pragma unroll
    for (int c = 0; c < NCOG; ++c)
#pragma unroll
      for (int q = 0; q < 4; ++q) {
        const int c0 = c * 32 + q * 8 + khf * 4;
#pragma unroll
        for (int vg = 0; vg < 4; ++vg) {
          const int gv = (vdb + (vg >> 1)) * 1024 + (vhb + (vg & 1) * 4) * 32 + vwb;
          u16x4 o;
#pragma unroll
          for (int rr = 0; rr < 4; ++rr) o[rr] = f2bf(acc[vg][c][q * 4 + rr]);
          *reinterpret_cast<u16x4*>(&dst[((size_t)b * S3 + gv) * COTOT + c0]) = o;
        }
      }
  }
}

// ------------------------------------------------------------- shortcut ----
__global__ __launch_bounds__(256) void shortcut_kernel(const float* __restrict__ x,
                                                       const float* __restrict__ wsc,
                                                       float* __restrict__ out) {
  const int b = blockIdx.y;
  const int v = blockIdx.x * 256 + threadIdx.x;
  __shared__ float lw[64 * 32];  // [ci][oc]
  for (int i = threadIdx.x; i < 2048; i += 256) {
    int ci = i >> 5, o = i & 31;
    lw[i] = wsc[o * 64 + ci];
  }
  __syncthreads();
  float acc[32];
#pragma unroll
  for (int o = 0; o < 32; ++o) acc[o] = 0.f;
  const float* xp = x + (size_t)b * 64 * S3 + v;
#pragma unroll 1
  for (int ci = 0; ci < 64; ++ci) {
    const float xv = xp[(size_t)ci * S3];
    const float4* wp = reinterpret_cast<const float4*>(&lw[ci << 5]);
#pragma unroll
    for (int o4 = 0; o4 < 8; ++o4) {
      float4 w4 = wp[o4];
      acc[o4 * 4 + 0] += xv * w4.x;
      acc[o4 * 4 + 1] += xv * w4.y;
      acc[o4 * 4 + 2] += xv * w4.z;
      acc[o4 * 4 + 3] += xv * w4.w;
    }
  }
  float* op = out + (size_t)b * 32 * S3 + v;
#pragma unroll
  for (int o = 0; o < 32; ++o) op[(size_t)o * S3] = acc[o];
}

// ---------------------------------------------------------------- launch ---
extern "C" void kernel_launch(void* const* d_in, const int* in_sizes, int n_in,
                              void* d_out, int out_size, void* d_ws, size_t ws_size,
                              hipStream_t stream) {
  const float* x       = (const float*)d_in[0];
  const int*   y       = (const int*)d_in[1];
  const float* s0_ws   = (const float*)d_in[2];
  const float* s0_bs   = (const float*)d_in[3];
  const float* s0_wg   = (const float*)d_in[4];
  const float* s0_bg   = (const float*)d_in[5];
  const float* s0_wb   = (const float*)d_in[6];
  const float* s0_bb   = (const float*)d_in[7];
  const float* s1_ws   = (const float*)d_in[8];
  const float* s1_bs   = (const float*)d_in[9];
  const float* s1_wg   = (const float*)d_in[10];
  const float* s1_bg   = (const float*)d_in[11];
  const float* s1_wb   = (const float*)d_in[12];
  const float* s1_bb   = (const float*)d_in[13];
  const float* conv0_w = (const float*)d_in[14];
  const float* conv0_b = (const float*)d_in[15];
  const float* conv1_w = (const float*)d_in[16];
  const float* conv1_b = (const float*)d_in[17];
  const float* convs_w = (const float*)d_in[18];

  float* out = (float*)d_out;
  char* ws = (char*)d_ws;
  short* xt    = (short*)(ws);               // [4][S3][64] bf16  16.78 MB
  short* actvT = (short*)(ws + 16777216);    // [4][S3][64]       16.78 MB
  short* hT    = (short*)(ws + 33554432);    // [4][S3][<=64]     16.78 MB
  short* d0T   = (short*)(ws + 50331648);    // [4][S3][32]        8.39 MB
  short* Wa0   = (short*)(ws + 58720256);
  short* Ws0   = (short*)(ws + 60817408);
  short* Wc0   = (short*)(ws + 62914560);
  short* Wa1   = (short*)(ws + 65011712);
  short* Ws1   = (short*)(ws + 67108864);
  short* Wc1   = (short*)(ws + 69206016);
  short* zp    = (short*)(ws + 70254592);    // 4KB zero page
  float* stats = (float*)(ws + 71303168);
  float* mu0 = stats, *rstd0 = stats + 256, *mu1 = stats + 512, *rstd1 = stats + 640;
  float* spart = stats + 1024;               // [4][64][64] partials
  short* Pext  = (short*)(ws + 71434240);    // [4][S3][64] bf16  (to 88.2 MB)

  hipMemsetAsync(zp, 0, 4096, stream);

  transpose_x<<<dim3(512, 4), 256, 0, stream>>>(x, xt);
  stats_kernel<<<dim3(256), 256, 0, stream>>>(x, mu0, rstd0);

  // weight repacks (per-b class selected) -> [b][27][KCH][CO2][16]
  repack_w<<<dim3(432, 4), 256, 0, stream>>>(s0_ws, nullptr, Wa0, y, 64, 64, 64,
                                             64L * 64 * 27, 0, 0, 110592);
  repack_w<<<dim3(864, 4), 256, 0, stream>>>(s0_wg, s0_wb, Ws0, y, 64, 128, 64,
                                             64L * 64 * 27, 64L * 64 * 27, 1, 221184);
  repack_w<<<dim3(216, 4), 256, 0, stream>>>(conv0_w, nullptr, Wc0, y, 32, 32, 64,
                                             0, 0, 0, 55296);
  repack_w<<<dim3(216, 4), 256, 0, stream>>>(s1_ws, nullptr, Wa1, y, 64, 64, 32,
                                             64L * 32 * 27, 0, 0, 55296);
  repack_w<<<dim3(432, 4), 256, 0, stream>>>(s1_wg, s1_wb, Ws1, y, 64, 64, 64,
                                             32L * 64 * 27, 32L * 64 * 27, 1, 110592);
  repack_w<<<dim3(108, 4), 256, 0, stream>>>(conv1_w, nullptr, Wc1, y, 32, 32, 32,
                                             0, 0, 0, 27648);

  // actv0 partials (K-split, z = kc half): P0 = hT, P1 = Pext
  conv_mfma<64, 64, 64, 5, 0, 2><<<dim3(64, 4, 2), 256, 0, stream>>>(
      xt, Wa0, nullptr, 0, y, nullptr, nullptr, nullptr, nullptr, nullptr, zp,
      nullptr, hT, Pext);
  // actvT = relu(P0 + P1 + s0_bs)
  combine_actv<<<dim3(1024, 4), 256, 0, stream>>>(hT, Pext, s0_bs, y, actvT);
  // h0 = lrelu(SPADE0(x; actv0))                   [B][S3][64]   2 blk/CU
  conv_mfma<64, 64, 128, 2, 64><<<dim3(64, 4, 2), 256, 0, stream>>>(
      actvT, Ws0, nullptr, 0, y, xt, mu0, rstd0, s0_bg, s0_bb, zp,
      nullptr, hT, nullptr);
  // dx0 = conv3(h0, conv0_w) + conv0_b             [B][S3][32]
  conv_mfma<64, 32, 32, 1, 0><<<dim3(64, 4, 1), 256, 0, stream>>>(
      hT, Wc0, conv0_b, 0, y, nullptr, nullptr, nullptr, nullptr, nullptr, zp,
      nullptr, d0T, nullptr);
  // instance-norm stats of dx0 (two-phase)
  stats_t32_p1<<<dim3(64, 4), 256, 0, stream>>>(d0T, spart);
  stats_t32_p2<<<dim3(1), 128, 0, stream>>>(spart, mu1, rstd1);
  // actv1 = relu(conv3(dx0, s1_ws) + s1_bs)        [B][S3][64]
  conv_mfma<32, 64, 64, 0, 0><<<dim3(64, 4, 1), 256, 0, stream>>>(
      d0T, Wa1, s1_bs, 64, y, nullptr, nullptr, nullptr, nullptr, nullptr, zp,
      nullptr, actvT, nullptr);
  // spade1 partials (K-split): P0 = xt (free after spade0), P1 = Pext
  conv_mfma<64, 64, 64, 5, 0, 2><<<dim3(64, 4, 2), 256, 0, stream>>>(
      actvT, Ws1, nullptr, 0, y, nullptr, nullptr, nullptr, nullptr, nullptr, zp,
      nullptr, xt, Pext);
  // hT = lrelu(SPADE epilogue of summed partials)
  combine_spade<<<dim3(512, 4), 256, 0, stream>>>(xt, Pext, d0T, mu1, rstd1,
                                                  s1_bg, s1_bb, y, hT);
  // out = conv1x1(x, convs_w)
  shortcut_kernel<<<dim3(128, 4), 256, 0, stream>>>(x, convs_w, out);
  // out += conv3(h1, conv1_w) + conv1_b
  conv_mfma<32, 32, 32, 4, 0><<<dim3(64, 4, 1), 256, 0, stream>>>(
      hT, Wc1, conv1_b, 0, y, nullptr, nullptr, nullptr, nullptr, nullptr, zp,
      out, nullptr, nullptr);
}

// Round 18
// 269.828 us; speedup vs baseline: 1.1249x; 1.1249x over previous
//
#include <hip/hip_runtime.h>

// SPADE ResNet block — bf16 MFMA implicit-GEMM, 32x32x16 MFMA.
// R18 = R14 conv pipeline (best: 284.8us) + tail consolidation:
//  (1) six repack launches merged into one repack_all (z = segment)
//  (2) shortcut reads bf16 xt (16.8 MB) instead of fp32 x (33.5 MB)
// Big convs are at the 2-barrier structural ceiling (~866 TF, MfmaUtil 35%);
// R8-R13/R15-R17 all failed to beat it. This round trims launch/memory tail.

#define S3 32768
constexpr float EPS = 1e-5f;

typedef __attribute__((ext_vector_type(8))) short s16x8;
typedef __attribute__((ext_vector_type(4))) float f32x4;
typedef __attribute__((ext_vector_type(16))) float f32x16;
typedef __attribute__((ext_vector_type(4))) unsigned short u16x4;
typedef __attribute__((ext_vector_type(8))) unsigned short u16x8;

#define GLL(g, l)                                                        \
  __builtin_amdgcn_global_load_lds(                                      \
      (const __attribute__((address_space(1))) void*)(g),                \
      (__attribute__((address_space(3))) void*)(l), 16, 0, 0)

__device__ __forceinline__ float bf2f(unsigned short u) {
  union { unsigned int i; float f; } v; v.i = ((unsigned int)u) << 16; return v.f;
}
__device__ __forceinline__ unsigned short f2bf(float f) {
  union { float f; unsigned int i; } v; v.f = f;
  unsigned int r = (v.i + 0x7FFFu + ((v.i >> 16) & 1u)) >> 16;
  return (unsigned short)r;
}

// ---------------------------------------------------------------- stats ----
__global__ __launch_bounds__(256) void stats_kernel(const float* __restrict__ x,
                                                    float* __restrict__ mu,
                                                    float* __restrict__ rstd) {
  const int bc = blockIdx.x;
  const float* p = x + (size_t)bc * S3;
  float s = 0.f, s2 = 0.f;
  for (int i = threadIdx.x; i < S3 / 4; i += 256) {
    float4 v = reinterpret_cast<const float4*>(p)[i];
    s  += v.x + v.y + v.z + v.w;
    s2 += v.x * v.x + v.y * v.y + v.z * v.z + v.w * v.w;
  }
  for (int off = 32; off; off >>= 1) {
    s  += __shfl_down(s, off, 64);
    s2 += __shfl_down(s2, off, 64);
  }
  __shared__ float ls[4], ls2[4];
  const int wid = threadIdx.x >> 6;
  if ((threadIdx.x & 63) == 0) { ls[wid] = s; ls2[wid] = s2; }
  __syncthreads();
  if (threadIdx.x == 0) {
    float S = 0.f, S2 = 0.f;
    for (int i = 0; i < 4; ++i) { S += ls[i]; S2 += ls2[i]; }
    const float m = S / (float)S3;
    const float var = S2 / (float)S3 - m * m;
    mu[bc] = m;
    rstd[bc] = rsqrtf(var + EPS);
  }
}

// Stats over bf16 T-layout tensor [B][S3][32] (dx0), phase 1.
__global__ __launch_bounds__(256) void stats_t32_p1(const short* __restrict__ t,
                                                    float* __restrict__ part) {
  const int b = blockIdx.y;
  const int chunk = blockIdx.x;
  const int tid = threadIdx.x;
  const int pq = tid & 3;
  float s[8], s2[8];
#pragma unroll
  for (int j = 0; j < 8; ++j) { s[j] = 0.f; s2[j] = 0.f; }
  const int vbase = chunk * 512;
#pragma unroll
  for (int v = tid >> 2; v < 512; v += 64) {
    u16x8 u = *reinterpret_cast<const u16x8*>(
        &t[((size_t)b * S3 + vbase + v) * 32 + pq * 8]);
#pragma unroll
    for (int j = 0; j < 8; ++j) { float f = bf2f(u[j]); s[j] += f; s2[j] += f * f; }
  }
#pragma unroll
  for (int off = 4; off < 64; off <<= 1) {
#pragma unroll
    for (int j = 0; j < 8; ++j) {
      s[j]  += __shfl_xor(s[j], off, 64);
      s2[j] += __shfl_xor(s2[j], off, 64);
    }
  }
  __shared__ float red[4][4][16];
  const int wv = tid >> 6, lane = tid & 63;
  if (lane < 4) {
#pragma unroll
    for (int j = 0; j < 8; ++j) { red[wv][lane][j] = s[j]; red[wv][lane][8 + j] = s2[j]; }
  }
  __syncthreads();
  if (tid < 32) {
    const int p = tid >> 3, j = tid & 7;
    float S = 0.f, S2 = 0.f;
#pragma unroll
    for (int w = 0; w < 4; ++w) { S += red[w][p][j]; S2 += red[w][p][8 + j]; }
    const int c = p * 8 + j;
    part[((size_t)(b * 64 + chunk)) * 64 + c] = S;
    part[((size_t)(b * 64 + chunk)) * 64 + 32 + c] = S2;
  }
}

__global__ __launch_bounds__(128) void stats_t32_p2(const float* __restrict__ part,
                                                    float* __restrict__ mu,
                                                    float* __restrict__ rstd) {
  const int tid = threadIdx.x;
  const int b = tid >> 5, c = tid & 31;
  float S = 0.f, S2 = 0.f;
#pragma unroll 4
  for (int k = 0; k < 64; ++k) {
    S  += part[((size_t)(b * 64 + k)) * 64 + c];
    S2 += part[((size_t)(b * 64 + k)) * 64 + 32 + c];
  }
  const float m = S / (float)S3;
  const float var = S2 / (float)S3 - m * m;
  mu[b * 32 + c] = m;
  rstd[b * 32 + c] = rsqrtf(var + EPS);
}

// ------------------------------------------------------------ transpose ----
__global__ __launch_bounds__(256) void transpose_x(const float* __restrict__ x,
                                                   short* __restrict__ xt) {
  const int b = blockIdx.y;
  const int v0 = blockIdx.x * 64;
  __shared__ unsigned short t[64][72];
  const int vox = threadIdx.x & 63;
  const int cg = threadIdx.x >> 6;
#pragma unroll
  for (int k = 0; k < 16; ++k) {
    const int ci = cg * 16 + k;
    t[vox][ci] = f2bf(x[((size_t)(b * 64 + ci)) * S3 + v0 + vox]);
  }
  __syncthreads();
  const int vv = threadIdx.x >> 2, part = threadIdx.x & 3;
  uint4 u0 = *reinterpret_cast<const uint4*>(&t[vv][part * 16]);
  uint4 u1 = *reinterpret_cast<const uint4*>(&t[vv][part * 16 + 8]);
  short* dst = &xt[((size_t)(b * S3 + v0 + vv)) * 64 + part * 16];
  *reinterpret_cast<uint4*>(dst) = u0;
  *reinterpret_cast<uint4*>(dst + 8) = u1;
}

// --------------------------------------------------------------- repack ----
// All six weight repacks in one launch; blockIdx.z = segment.
// fp32 [cls][CO_src][CI][27] -> bf16 [b][27][KCH=CI/16][CO2][16ci].
__global__ __launch_bounds__(256) void repack_all(
    const float* __restrict__ s0_ws, const float* __restrict__ s0_wg,
    const float* __restrict__ s0_wb, const float* __restrict__ conv0_w,
    const float* __restrict__ s1_ws, const float* __restrict__ s1_wg,
    const float* __restrict__ s1_wb, const float* __restrict__ conv1_w,
    short* __restrict__ Wa0, short* __restrict__ Ws0, short* __restrict__ Wc0,
    short* __restrict__ Wa1, short* __restrict__ Ws1, short* __restrict__ Wc1,
    const int* __restrict__ y) {
  const int b = blockIdx.y;
  const int seg = blockIdx.z;
  const int idx = blockIdx.x * 256 + threadIdx.x;
  const int cls = y[b];

  const float *wA = nullptr, *wB = nullptr;
  short* dst = nullptr;
  int CBLK = 64, CO2 = 64, CI = 64, paired = 0, total = 0;
  long clsA = 0, clsB = 0;
  switch (seg) {
    case 0: wA = s0_ws; dst = Wa0; CO2 = 64;  CI = 64; clsA = 64L * 64 * 27;
            total = 110592; break;
    case 1: wA = s0_wg; wB = s0_wb; dst = Ws0; CBLK = 64; CO2 = 128; CI = 64;
            clsA = clsB = 64L * 64 * 27; paired = 1; total = 221184; break;
    case 2: wA = conv0_w; dst = Wc0; CO2 = 32; CI = 64; total = 55296; break;
    case 3: wA = s1_ws; dst = Wa1; CO2 = 64; CI = 32; clsA = 64L * 32 * 27;
            total = 55296; break;
    case 4: wA = s1_wg; wB = s1_wb; dst = Ws1; CBLK = 64; CO2 = 64; CI = 64;
            clsA = clsB = 32L * 64 * 27; paired = 1; total = 110592; break;
    case 5: wA = conv1_w; dst = Wc1; CO2 = 32; CI = 32; total = 27648; break;
  }
  if (idx >= total) return;

  const int KCH = CI / 16;
  const int ci = idx & 15;
  const int co = (idx >> 4) % CO2;
  const int rest = idx / (16 * CO2);
  const int k16 = rest % KCH;
  const int tap = rest / KCH;
  const int srcch = k16 * 16 + ci;
  float v;
  if (paired) {
    const int H = CBLK >> 1;
    const int blk = co / CBLK, w = co % CBLK;
    if (w < H)
      v = wA[(size_t)clsA * cls + ((size_t)(blk * H + w) * CI + srcch) * 27 + tap];
    else
      v = wB[(size_t)clsB * cls + ((size_t)(blk * H + w - H) * CI + srcch) * 27 + tap];
  } else {
    v = wA[(size_t)clsA * cls + ((size_t)co * CI + srcch) * 27 + tap];
  }
  dst[(((size_t)(b * 27 + tap) * KCH + k16) * CO2 + co) * 16 + ci] = (short)f2bf(v);
}

// ------------------------------------------------------------ conv MFMA ----
// 8x8x8 tile, 4 waves, wave = CBLK co x 128 vox (VG=4). Per phase (kc,kd):
// sync; stage W (9 taps, lane-order) + X (kd==0, two-plane); sync; compute.
// EPI: 0 relu+bias->bf16T  1 bias->bf16T  2 SPADE+lrelu->bf16T (NCOG=2)
//      4 bias + accumulate into fp32 planar out
template <int CIN, int CBLK, int COTOT, int EPI, int NNORM>
__global__ __launch_bounds__(256, 2) void conv_mfma(
    const short* __restrict__ xt,      // [B][S3][CIN] bf16
    const short* __restrict__ W,       // [B][27][KCH][COTOT][16] bf16
    const float* __restrict__ bias,
    int bias_stride,
    const int* __restrict__ y,
    const short* __restrict__ xnb,     // EPI2: bf16 T [B][S3][NNORM]
    const float* __restrict__ mu,
    const float* __restrict__ rstd,
    const float* __restrict__ bgs,     // [NCLS][NNORM]
    const float* __restrict__ bbs,
    const short* __restrict__ zp,      // 4KB zero page
    float* __restrict__ outf,          // EPI4
    short* __restrict__ outb) {        // EPI 0..2
  constexpr int KCH = CIN / 16;
  constexpr int NCOG = CBLK / 32;
  constexpr int WG = 9 * NCOG * 64;                       // real W granules
  constexpr int WGP = ((WG + 255) / 256) * 256;           // padded
  constexpr int WISS = WGP / 256;

  __shared__ short ldsX[2048 * 8];     // [plane(khf)*1024 + halo slot][8]
  __shared__ short ldsW[WGP * 8];      // [(t9*NCOG+c)*64 + laneq][8]

  const int tid = threadIdx.x;
  const int lane = tid & 63, wid = tid >> 6;
  const int l31 = lane & 31, khf = lane >> 5;
  const int b = blockIdx.y;
  const int cls = y[b];
  const int co_base = blockIdx.z * CBLK;
  // XCD-aware tile swizzle: 64 tiles, 8 XCDs -> each XCD gets 8 contiguous
  const int tile = (blockIdx.x & 7) * 8 + (blockIdx.x >> 3);
  const int d0 = (tile >> 4) * 8, h0 = ((tile >> 2) & 3) * 8, w0 = (tile & 3) * 8;

  // X staging sources: granule i -> plane pl = i>>10, slot = i&1023 (10^3 halo)
  const short* gsrc[8];
#pragma unroll
  for (int k = 0; k < 8; ++k) {
    const int i = tid + k * 256;
    const int pl = i >> 10, slot = i & 1023;
    const short* g = zp;
    if (slot < 1000) {
      const int sd = slot / 100, r0 = slot - sd * 100;
      const int sh = r0 / 10, sw0 = r0 - sh * 10;
      const int gd = d0 + sd - 1, gh = h0 + sh - 1, gw = w0 + sw0 - 1;
      if ((unsigned)gd < 32u && (unsigned)gh < 32u && (unsigned)gw < 32u)
        g = xt + ((size_t)b * S3 + gd * 1024 + gh * 32 + gw) * CIN + pl * 8;
    }
    gsrc[k] = g;
  }

  auto stage_x = [&](int kc) {
#pragma unroll
    for (int k = 0; k < 8; ++k) {
      const int i = tid + k * 256;
      GLL(gsrc[k] + kc * 16, &ldsX[i * 8]);
    }
  };
  auto stage_w = [&](int kc, int kd) {
#pragma unroll
    for (int k = 0; k < WISS; ++k) {
      const int i = tid + k * 256;
      const short* g = zp;
      if (i < WG) {
        const int t9 = i / (NCOG * 64);
        const int r = i - t9 * (NCOG * 64);
        const int c = r >> 6, q = r & 63;
        g = W + (((size_t)(b * 27 + kd * 9 + t9) * KCH + kc) * COTOT +
                 co_base + c * 32 + (q & 31)) * 16 + (q >> 5) * 8;
      }
      GLL(g, &ldsW[i * 8]);
    }
  };

  f32x16 acc[4][NCOG];
#pragma unroll
  for (int v = 0; v < 4; ++v)
#pragma unroll
    for (int c = 0; c < NCOG; ++c)
#pragma unroll
      for (int r = 0; r < 16; ++r) acc[v][c][r] = 0.f;

  const int hw10 = (l31 >> 3) * 10 + (l31 & 7);
  const int xpl = khf * 1024;

#pragma unroll 1
  for (int kc = 0; kc < KCH; ++kc) {
#pragma unroll 1
    for (int kd = 0; kd < 3; ++kd) {
      __syncthreads();
      stage_w(kc, kd);
      if (kd == 0) stage_x(kc);
      __syncthreads();

      __builtin_amdgcn_s_setprio(1);
#pragma unroll
      for (int kh = 0; kh < 3; ++kh) {
#pragma unroll
        for (int kw = 0; kw < 3; ++kw) {
          const int t9 = kh * 3 + kw;
          s16x8 af[NCOG];
#pragma unroll
          for (int c = 0; c < NCOG; ++c)
            af[c] = *reinterpret_cast<const s16x8*>(
                &ldsW[((t9 * NCOG + c) * 64 + lane) * 8]);
          s16x8 bf[4];
#pragma unroll
          for (int vg = 0; vg < 4; ++vg) {
            const int slot = (2 * wid + (vg >> 1) + kd) * 100 +
                             ((vg & 1) * 4 + kh) * 10 + kw + hw10;
            bf[vg] = *reinterpret_cast<const s16x8*>(&ldsX[(xpl + slot) * 8]);
          }
#pragma unroll
          for (int c = 0; c < NCOG; ++c)
#pragma unroll
            for (int vg = 0; vg < 4; ++vg)
              acc[vg][c] = __builtin_amdgcn_mfma_f32_32x32x16_bf16(
                  af[c], bf[vg], acc[vg][c], 0, 0, 0);
        }
      }
      __builtin_amdgcn_s_setprio(0);
    }
  }

  // epilogue. C: col = lane&31 -> voxel, row = (reg&3)+8*(reg>>2)+4*khf -> co.
  const int vdb = d0 + 2 * wid;
  const int vhb = h0 + (l31 >> 3);
  const int vwb = w0 + (l31 & 7);

  if constexpr (EPI == 0 || EPI == 1) {
#pragma unroll
    for (int c = 0; c < NCOG; ++c)
#pragma unroll
      for (int q = 0; q < 4; ++q) {
        const int c0 = co_base + c * 32 + q * 8 + khf * 4;
        const f32x4 b4 = *reinterpret_cast<const f32x4*>(&bias[cls * bias_stride + c0]);
#pragma unroll
        for (int vg = 0; vg < 4; ++vg) {
          const int gv = (vdb + (vg >> 1)) * 1024 + (vhb + (vg & 1) * 4) * 32 + vwb;
          u16x4 o;
#pragma unroll
          for (int rr = 0; rr < 4; ++rr) {
            float v = acc[vg][c][q * 4 + rr] + b4[rr];
            if constexpr (EPI == 0) v = fmaxf(v, 0.f);
            o[rr] = f2bf(v);
          }
          *reinterpret_cast<u16x4*>(&outb[((size_t)b * S3 + gv) * COTOT + c0]) = o;
        }
      }
  }

  if constexpr (EPI == 2) {
    const int nb = blockIdx.z * 32;      // gamma = acc[.][0], beta = acc[.][1]
#pragma unroll
    for (int q = 0; q < 4; ++q) {
      const int c0 = nb + q * 8 + khf * 4;
      const f32x4 m4  = *reinterpret_cast<const f32x4*>(&mu[b * NNORM + c0]);
      const f32x4 r4  = *reinterpret_cast<const f32x4*>(&rstd[b * NNORM + c0]);
      const f32x4 g4  = *reinterpret_cast<const f32x4*>(&bgs[cls * NNORM + c0]);
      const f32x4 bb4 = *reinterpret_cast<const f32x4*>(&bbs[cls * NNORM + c0]);
#pragma unroll
      for (int vg = 0; vg < 4; ++vg) {
        const int gv = (vdb + (vg >> 1)) * 1024 + (vhb + (vg & 1) * 4) * 32 + vwb;
        const size_t vgl = (size_t)b * S3 + gv;
        u16x4 u = *reinterpret_cast<const u16x4*>(&xnb[vgl * NNORM + c0]);
        u16x4 o;
#pragma unroll
        for (int rr = 0; rr < 4; ++rr) {
          const float gamma = acc[vg][0][q * 4 + rr] + g4[rr];
          const float beta  = acc[vg][1][q * 4 + rr] + bb4[rr];
          const float nrm = (bf2f(u[rr]) - m4[rr]) * r4[rr];
          float h = nrm * (1.f + gamma) + beta;
          h = h > 0.f ? h : 0.2f * h;
          o[rr] = f2bf(h);
        }
        *reinterpret_cast<u16x4*>(&outb[vgl * NNORM + c0]) = o;
      }
    }
  }

  if constexpr (EPI == 4) {
#pragma unroll
    for (int q = 0; q < 4; ++q) {
      const int c0 = co_base + q * 8 + khf * 4;
      const f32x4 b4 = *reinterpret_cast<const f32x4*>(&bias[c0]);
#pragma unroll
      for (int vg = 0; vg < 4; ++vg) {
        const int gv = (vdb + (vg >> 1)) * 1024 + (vhb + (vg & 1) * 4) * 32 + vwb;
#pragma unroll
        for (int rr = 0; rr < 4; ++rr) {
          float* p = &outf[((size_t)(b * 32 + c0 + rr)) * S3 + gv];
          *p += acc[vg][0][q * 4 + rr] + b4[rr];
        }
      }
    }
  }
}

// ------------------------------------------------------------- shortcut ----
// 1x1x1 conv 64 -> 32, no bias. Reads bf16 xt [B][S3][64]; writes fp32 out.
__global__ __launch_bounds__(256) void shortcut_kernel(const short* __restrict__ xt,
                                                       const float* __restrict__ wsc,
                                                       float* __restrict__ out) {
  const int b = blockIdx.y;
  const int v = blockIdx.x * 256 + threadIdx.x;
  __shared__ float lw[64 * 32];  // [ci][oc]
  for (int i = threadIdx.x; i < 2048; i += 256) {
    int ci = i >> 5, o = i & 31;
    lw[i] = wsc[o * 64 + ci];
  }
  __syncthreads();
  float acc[32];
#pragma unroll
  for (int o = 0; o < 32; ++o) acc[o] = 0.f;
  const short* xp = xt + ((size_t)b * S3 + v) * 64;
#pragma unroll 1
  for (int cg = 0; cg < 8; ++cg) {
    u16x8 u = *reinterpret_cast<const u16x8*>(&xp[cg * 8]);
#pragma unroll
    for (int j = 0; j < 8; ++j) {
      const float xv = bf2f(u[j]);
      const float4* wp = reinterpret_cast<const float4*>(&lw[(cg * 8 + j) << 5]);
#pragma unroll
      for (int o4 = 0; o4 < 8; ++o4) {
        float4 w4 = wp[o4];
        acc[o4 * 4 + 0] += xv * w4.x;
        acc[o4 * 4 + 1] += xv * w4.y;
        acc[o4 * 4 + 2] += xv * w4.z;
        acc[o4 * 4 + 3] += xv * w4.w;
      }
    }
  }
  float* op = out + (size_t)b * 32 * S3 + v;
#pragma unroll
  for (int o = 0; o < 32; ++o) op[(size_t)o * S3] = acc[o];
}

// ---------------------------------------------------------------- launch ---
extern "C" void kernel_launch(void* const* d_in, const int* in_sizes, int n_in,
                              void* d_out, int out_size, void* d_ws, size_t ws_size,
                              hipStream_t stream) {
  const float* x       = (const float*)d_in[0];
  const int*   y       = (const int*)d_in[1];
  const float* s0_ws   = (const float*)d_in[2];
  const float* s0_bs   = (const float*)d_in[3];
  const float* s0_wg   = (const float*)d_in[4];
  const float* s0_bg   = (const float*)d_in[5];
  const float* s0_wb   = (const float*)d_in[6];
  const float* s0_bb   = (const float*)d_in[7];
  const float* s1_ws   = (const float*)d_in[8];
  const float* s1_bs   = (const float*)d_in[9];
  const float* s1_wg   = (const float*)d_in[10];
  const float* s1_bg   = (const float*)d_in[11];
  const float* s1_wb   = (const float*)d_in[12];
  const float* s1_bb   = (const float*)d_in[13];
  const float* conv0_w = (const float*)d_in[14];
  const float* conv0_b = (const float*)d_in[15];
  const float* conv1_w = (const float*)d_in[16];
  const float* conv1_b = (const float*)d_in[17];
  const float* convs_w = (const float*)d_in[18];

  float* out = (float*)d_out;
  char* ws = (char*)d_ws;
  short* xt    = (short*)(ws);               // [4][S3][64] bf16  16.78 MB
  short* actvT = (short*)(ws + 16777216);    // [4][S3][64]       16.78 MB
  short* hT    = (short*)(ws + 33554432);    // [4][S3][<=64]     16.78 MB
  short* d0T   = (short*)(ws + 50331648);    // [4][S3][32]        8.39 MB
  short* Wa0   = (short*)(ws + 58720256);
  short* Ws0   = (short*)(ws + 60817408);
  short* Wc0   = (short*)(ws + 62914560);
  short* Wa1   = (short*)(ws + 65011712);
  short* Ws1   = (short*)(ws + 67108864);
  short* Wc1   = (short*)(ws + 69206016);
  short* zp    = (short*)(ws + 70254592);    // 4KB zero page
  float* stats = (float*)(ws + 71303168);
  float* mu0 = stats, *rstd0 = stats + 256, *mu1 = stats + 512, *rstd1 = stats + 640;
  float* spart = stats + 1024;               // [4][64][64] partials

  hipMemsetAsync(zp, 0, 4096, stream);

  transpose_x<<<dim3(512, 4), 256, 0, stream>>>(x, xt);
  stats_kernel<<<dim3(256), 256, 0, stream>>>(x, mu0, rstd0);

  // all weight repacks in one launch (z = segment)
  repack_all<<<dim3(864, 4, 6), 256, 0, stream>>>(
      s0_ws, s0_wg, s0_wb, conv0_w, s1_ws, s1_wg, s1_wb, conv1_w,
      Wa0, Ws0, Wc0, Wa1, Ws1, Wc1, y);

  // actv0 = relu(conv3(x, s0_ws) + s0_bs)          [B][S3][64]
  conv_mfma<64, 64, 64, 0, 0><<<dim3(64, 4, 1), 256, 0, stream>>>(
      xt, Wa0, s0_bs, 64, y, nullptr, nullptr, nullptr, nullptr, nullptr, zp,
      nullptr, actvT);
  // h0 = lrelu(SPADE0(x; actv0))                   [B][S3][64]
  conv_mfma<64, 64, 128, 2, 64><<<dim3(64, 4, 2), 256, 0, stream>>>(
      actvT, Ws0, nullptr, 0, y, xt, mu0, rstd0, s0_bg, s0_bb, zp,
      nullptr, hT);
  // dx0 = conv3(h0, conv0_w) + conv0_b             [B][S3][32]
  conv_mfma<64, 32, 32, 1, 0><<<dim3(64, 4, 1), 256, 0, stream>>>(
      hT, Wc0, conv0_b, 0, y, nullptr, nullptr, nullptr, nullptr, nullptr, zp,
      nullptr, d0T);
  // instance-norm stats of dx0 (two-phase)
  stats_t32_p1<<<dim3(64, 4), 256, 0, stream>>>(d0T, spart);
  stats_t32_p2<<<dim3(1), 128, 0, stream>>>(spart, mu1, rstd1);
  // actv1 = relu(conv3(dx0, s1_ws) + s1_bs)        [B][S3][64]
  conv_mfma<32, 64, 64, 0, 0><<<dim3(64, 4, 1), 256, 0, stream>>>(
      d0T, Wa1, s1_bs, 64, y, nullptr, nullptr, nullptr, nullptr, nullptr, zp,
      nullptr, actvT);
  // h1 = lrelu(SPADE1(dx0; actv1))                 [B][S3][32]
  conv_mfma<64, 64, 64, 2, 32><<<dim3(64, 4, 1), 256, 0, stream>>>(
      actvT, Ws1, nullptr, 0, y, d0T, mu1, rstd1, s1_bg, s1_bb, zp,
      nullptr, hT);
  // out = conv1x1(x, convs_w)  (reads bf16 xt)
  shortcut_kernel<<<dim3(128, 4), 256, 0, stream>>>(xt, convs_w, out);
  // out += conv3(h1, conv1_w) + conv1_b
  conv_mfma<32, 32, 32, 4, 0><<<dim3(64, 4, 1), 256, 0, stream>>>(
      hT, Wc1, conv1_b, 0, y, nullptr, nullptr, nullptr, nullptr, nullptr, zp,
      out, nullptr);
}